// Round 13
// baseline (76.482 us; speedup 1.0000x reference)
//
#include <hip/hip_runtime.h>

#define S 2048
#define B 2
#define H 1024
#define NH 16
#define HD 64
#define THREE_H 3072
#define ROWS (S*B)   // 4096

typedef __attribute__((ext_vector_type(8))) short short8;
typedef __attribute__((ext_vector_type(4))) float f32x4;
typedef const __attribute__((address_space(1))) unsigned int* gptr_t;
typedef __attribute__((address_space(3))) unsigned int* lptr_t;

#define N8_A (ROWS * H / 8)        // 524288
#define N8_W (THREE_H * H / 8)     // 393216

__device__ __forceinline__ ushort f2bf(float f) {
    union { float f; unsigned u; } v; v.f = f;
    unsigned r = v.u + 0x7fffu + ((v.u >> 16) & 1u);
    return (ushort)(r >> 16);
}
__device__ __forceinline__ float bf2f(ushort u) {
    union { unsigned u; float f; } v; v.u = ((unsigned)u) << 16;
    return v.f;
}

// ---------------------------------------------------------------------------
// Cast f32 -> bf16 for A and W in one launch
// ---------------------------------------------------------------------------
__global__ void cast_both(const float* __restrict__ A, const float* __restrict__ W,
                          ushort* __restrict__ Ab, ushort* __restrict__ Wb) {
    int i = blockIdx.x * 256 + threadIdx.x;
    const float4* s4;
    ushort* dst;
    if (i < N8_A) { s4 = (const float4*)A; dst = Ab; }
    else if (i < N8_A + N8_W) { s4 = (const float4*)W; dst = Wb; i -= N8_A; }
    else return;
    float4 a = s4[2 * i], b = s4[2 * i + 1];
    short8 o;
    o[0] = f2bf(a.x); o[1] = f2bf(a.y); o[2] = f2bf(a.z); o[3] = f2bf(a.w);
    o[4] = f2bf(b.x); o[5] = f2bf(b.y); o[6] = f2bf(b.z); o[7] = f2bf(b.w);
    *(short8*)(dst + 8 * (size_t)i) = o;
}

// ---------------------------------------------------------------------------
// K1: bf16 MFMA GEMM. R12 structure (128x128 tile, 8 waves, BK=32,
// conflict-free XOR swizzle) + 2-phase double-buffered pipeline: STAGE the
// NEXT K-tile before computing the current one -> the vmcnt(0) drain at the
// barrier covers loads issued a compute-phase earlier (T3-minimum schedule).
// ---------------------------------------------------------------------------
__global__ __launch_bounds__(512) void qkv_gemm_mfma(const ushort* __restrict__ Abf,
                                                     const ushort* __restrict__ Wbf,
                                                     const float* __restrict__ bias,
                                                     ushort* __restrict__ Qb,
                                                     ushort* __restrict__ Ktd,
                                                     ushort* __restrict__ Vtd) {
    __shared__ ushort Abuf[2][128 * 32];   // 16 KB
    __shared__ ushort Bbuf[2][128 * 32];   // 16 KB
    const int tid = threadIdx.x;
    const int wave = tid >> 6, lane = tid & 63;
    const int wr = wave >> 1, wc = wave & 1;     // 4x2 wave grid
    const int row0 = blockIdx.x * 128;
    const int col0 = blockIdx.y * 128;

    f32x4 acc[2][4] = {};

    const int lrow = lane >> 2;                             // 0..15 row in 16-row chunk
    const int gk = ((lane & 3) ^ ((lrow >> 1) & 3)) * 8;    // inverse-swizzled src octet
    const int il = lane & 15, ko = lane >> 4;

    const size_t arow = (size_t)(row0 + wave * 16 + lrow) * H + gk;
    const size_t wrow = (size_t)(col0 + wave * 16 + lrow) * H + gk;
    const int ldst = wave * 512 + lane * 8;

#define STAGE(buf, k0)                                                      \
    {                                                                       \
        __builtin_amdgcn_global_load_lds((gptr_t)&Abf[arow + (k0)],         \
            (lptr_t)&Abuf[buf][ldst], 16, 0, 0);                            \
        __builtin_amdgcn_global_load_lds((gptr_t)&Wbf[wrow + (k0)],         \
            (lptr_t)&Bbuf[buf][ldst], 16, 0, 0);                            \
    }

#define COMPUTE(buf)                                                        \
    {                                                                       \
        short8 af[2], bfr[4];                                               \
        _Pragma("unroll")                                                   \
        for (int m = 0; m < 2; ++m) {                                       \
            int ar = wr * 32 + m * 16 + il;                                 \
            af[m] = *(const short8*)&Abuf[buf][ar * 32 + (ko ^ ((ar >> 1) & 3)) * 8]; \
        }                                                                   \
        _Pragma("unroll")                                                   \
        for (int n = 0; n < 4; ++n) {                                       \
            int br = wc * 64 + n * 16 + il;                                 \
            bfr[n] = *(const short8*)&Bbuf[buf][br * 32 + (ko ^ ((br >> 1) & 3)) * 8]; \
        }                                                                   \
        _Pragma("unroll")                                                   \
        for (int m = 0; m < 2; ++m)                                         \
            _Pragma("unroll")                                               \
            for (int n = 0; n < 4; ++n)                                     \
                acc[m][n] = __builtin_amdgcn_mfma_f32_16x16x32_bf16(af[m], bfr[n], acc[m][n], 0, 0, 0); \
    }

    // prologue: stage tile 0, drain, enter steady state
    STAGE(0, 0);
    __syncthreads();
    int cur = 0;
    for (int t = 0; t < 31; ++t) {
        STAGE(cur ^ 1, (t + 1) * 32);   // issue next tile (stays in flight over compute)
        COMPUTE(cur);
        __syncthreads();                 // drains vmcnt: next tile ready; buf[cur] free
        cur ^= 1;
    }
    COMPUTE(cur);                        // last tile, no further staging
#undef STAGE
#undef COMPUTE

    // ---- epilogue (R9-proven scatter; wave rows = wr*32 + m*16) ----
#pragma unroll
    for (int n = 0; n < 4; ++n) {
        int cbase = col0 + wc * 64 + n * 16;     // within one 64-col (h,sel) segment
        int h   = cbase / 192;
        int r3  = cbase % 192;
        int sel = r3 >> 6;                       // 0=q 1=k 2=v, wave-uniform
        int d   = (r3 & 63) + il;
        float bv = bias[cbase + il];
        if (sel == 0) {
#pragma unroll
            for (int m = 0; m < 2; ++m) {
                int rowb = row0 + wr * 32 + m * 16 + ko * 4;
#pragma unroll
                for (int j = 0; j < 4; ++j) {
                    int r = rowb + j;
                    int s = r >> 1, b = r & 1;   // r = s*B + b, B=2
                    Qb[((size_t)((b * NH + h) * S + s)) * HD + d] = f2bf(acc[m][n][j] + bv);
                }
            }
        } else {
            ushort* dst = (sel == 1) ? Ktd : Vtd;
            const size_t ro0 = ((size_t)(h)      * HD + d) * S;   // b=0 row
            const size_t ro1 = ((size_t)(NH + h) * HD + d) * S;   // b=1 row
#pragma unroll
            for (int m = 0; m < 2; ++m) {
                int t0 = (row0 + wr * 32 + m * 16 + ko * 4) >> 1;  // even
                uint lo = (uint)f2bf(acc[m][n][0] + bv) |
                          ((uint)f2bf(acc[m][n][2] + bv) << 16);   // t0,t0+1 (b=0)
                uint hi = (uint)f2bf(acc[m][n][1] + bv) |
                          ((uint)f2bf(acc[m][n][3] + bv) << 16);   // t0,t0+1 (b=1)
                *(uint*)&dst[ro0 + t0] = lo;
                *(uint*)&dst[ro1 + t0] = hi;
            }
        }
    }
}

// ---------------------------------------------------------------------------
// V suffix-scan, one wave per (bh,d) row of 2048 t, in place on Vtd. (R9)
// ---------------------------------------------------------------------------
__global__ __launch_bounds__(256) void vscan(ushort* __restrict__ Vtd) {
    const int row = blockIdx.x * 4 + (threadIdx.x >> 6);  // 0..2047 = bh*64+d
    const int lane = threadIdx.x & 63;
    ushort* vp = Vtd + (size_t)row * S + lane * 32;
    float v[32];
#pragma unroll
    for (int q = 0; q < 4; ++q) {
        short8 x = *(const short8*)(vp + q * 8);
#pragma unroll
        for (int k = 0; k < 8; ++k) v[q * 8 + k] = bf2f((ushort)x[k]);
    }
    float sum = 0.f;
#pragma unroll
    for (int k = 0; k < 32; ++k) sum += v[k];
    float t = sum;
#pragma unroll
    for (int off = 1; off < 64; off <<= 1) {
        float o = __shfl_down(t, off, 64);
        if (lane + off < 64) t += o;
    }
    float acc = t - sum;   // exclusive suffix (sum of lanes > lane)
#pragma unroll
    for (int k = 31; k >= 0; --k) { acc += v[k]; v[k] = acc; }
#pragma unroll
    for (int q = 0; q < 4; ++q) {
        short8 o;
#pragma unroll
        for (int k = 0; k < 8; ++k) o[k] = f2bf(v[q * 8 + k]);
        *(short8*)(vp + q * 8) = o;
    }
}

// ---------------------------------------------------------------------------
// K3: M[i][j] = sum_t Ktd[i][t]*Vtd[j][t] via MFMA; cross-wave LDS reduce
// -> Mpart has 4 slices. (R9-proven)
// ---------------------------------------------------------------------------
__global__ __launch_bounds__(256) void kvm_mfma(const ushort* __restrict__ Kt,
                                                const ushort* __restrict__ Vt,
                                                float* __restrict__ Mpart) {
    __shared__ float red[2][4096];   // 32 KB
    const int bh = blockIdx.x, kb = blockIdx.y;
    const int tid = threadIdx.x, wave = tid >> 6, lane = tid & 63;
    const int slice = kb * 4 + wave;
    const ushort* Kp = Kt + (size_t)bh * HD * S;
    const ushort* Vp = Vt + (size_t)bh * HD * S;
    f32x4 acc[4][4] = {};
    const int il = lane & 15, g = lane >> 4;
    const int tbase = slice * 128 + g * 8;
#pragma unroll
    for (int ks = 0; ks < 4; ++ks) {
        const int t = tbase + ks * 32;
        short8 af[4], bfv[4];
#pragma unroll
        for (int m = 0; m < 4; ++m) af[m]  = *(const short8*)&Kp[(size_t)(m * 16 + il) * S + t];
#pragma unroll
        for (int n = 0; n < 4; ++n) bfv[n] = *(const short8*)&Vp[(size_t)(n * 16 + il) * S + t];
#pragma unroll
        for (int m = 0; m < 4; ++m)
#pragma unroll
            for (int n = 0; n < 4; ++n)
                acc[m][n] = __builtin_amdgcn_mfma_f32_16x16x32_bf16(af[m], bfv[n], acc[m][n], 0, 0, 0);
    }
#define DUMP(dstbuf)                                                        \
    { float* _d = (dstbuf);                                                 \
      _Pragma("unroll") for (int m = 0; m < 4; ++m)                         \
      _Pragma("unroll") for (int n = 0; n < 4; ++n)                         \
      _Pragma("unroll") for (int j = 0; j < 4; ++j)                         \
          _d[(m * 16 + g * 4 + j) * 64 + n * 16 + il] = acc[m][n][j]; }
#define ADDIN(srcbuf)                                                       \
    { const float* _s = (srcbuf);                                           \
      _Pragma("unroll") for (int m = 0; m < 4; ++m)                         \
      _Pragma("unroll") for (int n = 0; n < 4; ++n)                         \
      _Pragma("unroll") for (int j = 0; j < 4; ++j)                         \
          acc[m][n][j] += _s[(m * 16 + g * 4 + j) * 64 + n * 16 + il]; }
    if (wave == 1) DUMP(red[0]);
    if (wave == 3) DUMP(red[1]);
    __syncthreads();
    if (wave == 0) ADDIN(red[0]);
    if (wave == 2) ADDIN(red[1]);
    __syncthreads();
    if (wave == 2) DUMP(red[0]);
    __syncthreads();
    if (wave == 0) {
        ADDIN(red[0]);
        float* Mp = Mpart + ((size_t)kb * 32 + bh) * 4096;
#pragma unroll
        for (int m = 0; m < 4; ++m)
#pragma unroll
            for (int n = 0; n < 4; ++n)
#pragma unroll
                for (int j = 0; j < 4; ++j)
                    Mp[(m * 16 + g * 4 + j) * 64 + n * 16 + il] = acc[m][n][j];
    }
#undef DUMP
#undef ADDIN
}

// ---------------------------------------------------------------------------
// K4: out = scale * Q·M via MFMA; folds the 4-slice Mpart reduce. (R9)
// ---------------------------------------------------------------------------
__global__ __launch_bounds__(256) void qm_mfma(const ushort* __restrict__ Qb,
                                               const float* __restrict__ Mpart,
                                               float* __restrict__ out) {
    __shared__ ushort Mt[64][72];   // Mt[d][i] = M[i][d], bf16
    const int bh = blockIdx.x, b = bh >> 4, h = bh & 15;
    const int tid = threadIdx.x;
    {
        const int i = tid >> 2, jq = (tid & 3) * 16;
        f32x4 s0 = {}, s1 = {}, s2 = {}, s3 = {};
#pragma unroll
        for (int sl = 0; sl < 4; ++sl) {
            const float* p = Mpart + ((size_t)sl * 32 + bh) * 4096 + i * 64 + jq;
            s0 += *(const f32x4*)(p);
            s1 += *(const f32x4*)(p + 4);
            s2 += *(const f32x4*)(p + 8);
            s3 += *(const f32x4*)(p + 12);
        }
#pragma unroll
        for (int k = 0; k < 4; ++k) {
            Mt[jq + 0  + k][i] = f2bf(s0[k]);
            Mt[jq + 4  + k][i] = f2bf(s1[k]);
            Mt[jq + 8  + k][i] = f2bf(s2[k]);
            Mt[jq + 12 + k][i] = f2bf(s3[k]);
        }
    }
    __syncthreads();
    const int wave = tid >> 6, lane = tid & 63;
    const int sl15 = lane & 15, koct = (lane >> 4) * 8;
    const int s0b = blockIdx.y * 256 + wave * 64;
    f32x4 acc[4][4] = {};
#pragma unroll
    for (int ks = 0; ks < 2; ++ks) {
        short8 af[4], bfv[4];
#pragma unroll
        for (int m = 0; m < 4; ++m) {
            int s = s0b + m * 16 + sl15;
            af[m] = *(const short8*)&Qb[((size_t)bh * S + s) * HD + ks * 32 + koct];
        }
#pragma unroll
        for (int n = 0; n < 4; ++n)
            bfv[n] = *(const short8*)&Mt[n * 16 + sl15][ks * 32 + koct];
#pragma unroll
        for (int m = 0; m < 4; ++m)
#pragma unroll
            for (int n = 0; n < 4; ++n)
                acc[m][n] = __builtin_amdgcn_mfma_f32_16x16x32_bf16(af[m], bfv[n], acc[m][n], 0, 0, 0);
    }
    const float scale = 0.125f * 0.02209708691207961f;  // HD^-0.5 * S^-0.5
#pragma unroll
    for (int m = 0; m < 4; ++m)
#pragma unroll
        for (int n = 0; n < 4; ++n)
#pragma unroll
            for (int j = 0; j < 4; ++j) {
                int s = s0b + m * 16 + (lane >> 4) * 4 + j;
                int d = n * 16 + sl15;
                out[(size_t)(s * B + b) * H + h * 64 + d] = acc[m][n][j] * scale;
            }
}

// ---------------------------------------------------------------------------
extern "C" void kernel_launch(void* const* d_in, const int* in_sizes, int n_in,
                              void* d_out, int out_size, void* d_ws, size_t ws_size,
                              hipStream_t stream) {
    const float* hidden = (const float*)d_in[0];
    const float* W      = (const float*)d_in[1];
    const float* bias   = (const float*)d_in[2];
    float* out = (float*)d_out;

    ushort* Qb    = (ushort*)d_ws;                      //  8 MB  [bh][s][d]
    ushort* Ktd   = Qb + 4194304;                       //  8 MB  [bh][d][t]
    ushort* Vtd   = Ktd + 4194304;                      //  8 MB  [bh][d][t] (scan in place)
    float*  Mpart = (float*)(Vtd + 4194304);            //  2 MB  [4][bh][64][64]
    ushort* Abf   = (ushort*)(Mpart + 524288);          //  8 MB
    ushort* Wbf   = Abf + 4194304;                      //  6 MB
    // total ~40 MB of d_ws

    cast_both<<<(N8_A + N8_W + 255) / 256, 256, 0, stream>>>(hidden, W, Abf, Wbf);
    qkv_gemm_mfma<<<dim3(ROWS / 128, THREE_H / 128), 512, 0, stream>>>(Abf, Wbf, bias, Qb, Ktd, Vtd);
    vscan<<<512, 256, 0, stream>>>(Vtd);
    kvm_mfma<<<dim3(32, 4), 256, 0, stream>>>(Ktd, Vtd, Mpart);
    qm_mfma<<<dim3(32, 8), 256, 0, stream>>>(Qb, Mpart, out);
}

// Round 14
// 75.243 us; speedup vs baseline: 1.0165x; 1.0165x over previous
//
#include <hip/hip_runtime.h>

#define S 2048
#define B 2
#define H 1024
#define NH 16
#define HD 64
#define THREE_H 3072
#define ROWS (S*B)   // 4096

typedef __attribute__((ext_vector_type(8))) short short8;
typedef __attribute__((ext_vector_type(4))) float f32x4;
typedef const __attribute__((address_space(1))) unsigned int* gptr_t;
typedef __attribute__((address_space(3))) unsigned int* lptr_t;

#define N8_A (ROWS * H / 8)        // 524288
#define N8_W (THREE_H * H / 8)     // 393216

__device__ __forceinline__ ushort f2bf(float f) {
    union { float f; unsigned u; } v; v.f = f;
    unsigned r = v.u + 0x7fffu + ((v.u >> 16) & 1u);
    return (ushort)(r >> 16);
}
__device__ __forceinline__ float bf2f(ushort u) {
    union { unsigned u; float f; } v; v.u = ((unsigned)u) << 16;
    return v.f;
}

// ---------------------------------------------------------------------------
// Cast f32 -> bf16 for A and W in one launch (R12-proven)
// ---------------------------------------------------------------------------
__global__ void cast_both(const float* __restrict__ A, const float* __restrict__ W,
                          ushort* __restrict__ Ab, ushort* __restrict__ Wb) {
    int i = blockIdx.x * 256 + threadIdx.x;
    const float4* s4;
    ushort* dst;
    if (i < N8_A) { s4 = (const float4*)A; dst = Ab; }
    else if (i < N8_A + N8_W) { s4 = (const float4*)W; dst = Wb; i -= N8_A; }
    else return;
    float4 a = s4[2 * i], b = s4[2 * i + 1];
    short8 o;
    o[0] = f2bf(a.x); o[1] = f2bf(a.y); o[2] = f2bf(a.z); o[3] = f2bf(a.w);
    o[4] = f2bf(b.x); o[5] = f2bf(b.y); o[6] = f2bf(b.z); o[7] = f2bf(b.w);
    *(short8*)(dst + 8 * (size_t)i) = o;
}

// ---------------------------------------------------------------------------
// K1: bf16 MFMA GEMM, counted-vmcnt pipeline (T3+T4):
//   128x128 tile, 8 waves (4x2), BK=64 double-buffered (64 KB LDS).
//   Prologue stages tiles 0,1. Loop: vmcnt(4) [tile t ready, t+1 in flight]
//   -> raw s_barrier -> compute (12 ds_read + 16 MFMA, setprio) -> s_barrier
//   -> STAGE tile t+2 into freed buffer. vmcnt never drains mid-loop.
//   BK=64 XOR swizzle (R7-verified 0 conflicts): content(row,slot)=slot^(row&7).
//   Epilogue: R12-proven scatter (Q->[bh][s][d]; K,V->[bh][d][t] packed uint).
// ---------------------------------------------------------------------------
__global__ __launch_bounds__(512) void qkv_gemm_mfma(const ushort* __restrict__ Abf,
                                                     const ushort* __restrict__ Wbf,
                                                     const float* __restrict__ bias,
                                                     ushort* __restrict__ Qb,
                                                     ushort* __restrict__ Ktd,
                                                     ushort* __restrict__ Vtd) {
    __shared__ ushort Abuf[2][128 * 64];   // 32 KB
    __shared__ ushort Bbuf[2][128 * 64];   // 32 KB
    const int tid = threadIdx.x;
    const int wave = tid >> 6, lane = tid & 63;
    const int wr = wave >> 1, wc = wave & 1;     // 4x2 wave grid
    const int row0 = blockIdx.x * 128;
    const int col0 = blockIdx.y * 128;

    f32x4 acc[2][4] = {};

    const int srow = lane >> 3;                       // 0..7 row within 8-row chunk
    const int gk = ((lane & 7) ^ srow) * 8;           // inverse-swizzled source octet
    const int il = lane & 15, ko = lane >> 4;

    const size_t arow0 = (size_t)(row0 + wave * 16 + srow) * H + gk;
    const size_t arow1 = arow0 + (size_t)8 * H;
    const size_t wrow0 = (size_t)(col0 + wave * 16 + srow) * H + gk;
    const size_t wrow1 = wrow0 + (size_t)8 * H;
    const int ld0 = (wave * 16) * 64 + lane * 8;      // linear dest, lane*16B
    const int ld1 = ld0 + 8 * 64;

#define STAGE(buf, k0)                                                        \
    {                                                                         \
        __builtin_amdgcn_global_load_lds((gptr_t)&Abf[arow0 + (k0)],          \
            (lptr_t)&Abuf[buf][ld0], 16, 0, 0);                               \
        __builtin_amdgcn_global_load_lds((gptr_t)&Wbf[wrow0 + (k0)],          \
            (lptr_t)&Bbuf[buf][ld0], 16, 0, 0);                               \
        __builtin_amdgcn_global_load_lds((gptr_t)&Abf[arow1 + (k0)],          \
            (lptr_t)&Abuf[buf][ld1], 16, 0, 0);                               \
        __builtin_amdgcn_global_load_lds((gptr_t)&Wbf[wrow1 + (k0)],          \
            (lptr_t)&Bbuf[buf][ld1], 16, 0, 0);                               \
    }

    // prologue: stage tiles 0 and 1 (8 loads outstanding per wave)
    STAGE(0, 0);
    STAGE(1, 64);

    int cur = 0;
    for (int t = 0; t < 16; ++t) {
        if (t < 15) { asm volatile("s_waitcnt vmcnt(4)" ::: "memory"); }
        else        { asm volatile("s_waitcnt vmcnt(0)" ::: "memory"); }
        __builtin_amdgcn_s_barrier();          // tile t fully in LDS (all waves)
        __builtin_amdgcn_sched_barrier(0);

#pragma unroll
        for (int kh = 0; kh < 2; ++kh) {       // two 32-k halves of the 64-k tile
            short8 af[2], bfr[4];
#pragma unroll
            for (int m = 0; m < 2; ++m) {
                int ar = wr * 32 + m * 16 + il;
                af[m] = *(const short8*)&Abuf[cur][ar * 64 + ((kh * 4 + ko) ^ (ar & 7)) * 8];
            }
#pragma unroll
            for (int n = 0; n < 4; ++n) {
                int br = wc * 64 + n * 16 + il;
                bfr[n] = *(const short8*)&Bbuf[cur][br * 64 + ((kh * 4 + ko) ^ (br & 7)) * 8];
            }
            __builtin_amdgcn_s_setprio(1);
#pragma unroll
            for (int m = 0; m < 2; ++m)
#pragma unroll
                for (int n = 0; n < 4; ++n)
                    acc[m][n] = __builtin_amdgcn_mfma_f32_16x16x32_bf16(af[m], bfr[n], acc[m][n], 0, 0, 0);
            __builtin_amdgcn_s_setprio(0);
        }

        __builtin_amdgcn_s_barrier();          // all waves done reading buf[cur]
        __builtin_amdgcn_sched_barrier(0);
        if (t < 14) STAGE(cur, (t + 2) * 64);  // refill freed buffer; stays in flight
        cur ^= 1;
    }
#undef STAGE

    // ---- epilogue (R12-proven scatter; wave rows = wr*32 + m*16) ----
#pragma unroll
    for (int n = 0; n < 4; ++n) {
        int cbase = col0 + wc * 64 + n * 16;     // within one 64-col (h,sel) segment
        int h   = cbase / 192;
        int r3  = cbase % 192;
        int sel = r3 >> 6;                       // 0=q 1=k 2=v, wave-uniform
        int d   = (r3 & 63) + il;
        float bv = bias[cbase + il];
        if (sel == 0) {
#pragma unroll
            for (int m = 0; m < 2; ++m) {
                int rowb = row0 + wr * 32 + m * 16 + ko * 4;
#pragma unroll
                for (int j = 0; j < 4; ++j) {
                    int r = rowb + j;
                    int s = r >> 1, b = r & 1;   // r = s*B + b, B=2
                    Qb[((size_t)((b * NH + h) * S + s)) * HD + d] = f2bf(acc[m][n][j] + bv);
                }
            }
        } else {
            ushort* dst = (sel == 1) ? Ktd : Vtd;
            const size_t ro0 = ((size_t)(h)      * HD + d) * S;   // b=0 row
            const size_t ro1 = ((size_t)(NH + h) * HD + d) * S;   // b=1 row
#pragma unroll
            for (int m = 0; m < 2; ++m) {
                int t0 = (row0 + wr * 32 + m * 16 + ko * 4) >> 1;  // even
                uint lo = (uint)f2bf(acc[m][n][0] + bv) |
                          ((uint)f2bf(acc[m][n][2] + bv) << 16);   // t0,t0+1 (b=0)
                uint hi = (uint)f2bf(acc[m][n][1] + bv) |
                          ((uint)f2bf(acc[m][n][3] + bv) << 16);   // t0,t0+1 (b=1)
                *(uint*)&dst[ro0 + t0] = lo;
                *(uint*)&dst[ro1 + t0] = hi;
            }
        }
    }
}

// ---------------------------------------------------------------------------
// V suffix-scan, one wave per (bh,d) row of 2048 t, in place on Vtd. (R12)
// ---------------------------------------------------------------------------
__global__ __launch_bounds__(256) void vscan(ushort* __restrict__ Vtd) {
    const int row = blockIdx.x * 4 + (threadIdx.x >> 6);  // 0..2047 = bh*64+d
    const int lane = threadIdx.x & 63;
    ushort* vp = Vtd + (size_t)row * S + lane * 32;
    float v[32];
#pragma unroll
    for (int q = 0; q < 4; ++q) {
        short8 x = *(const short8*)(vp + q * 8);
#pragma unroll
        for (int k = 0; k < 8; ++k) v[q * 8 + k] = bf2f((ushort)x[k]);
    }
    float sum = 0.f;
#pragma unroll
    for (int k = 0; k < 32; ++k) sum += v[k];
    float t = sum;
#pragma unroll
    for (int off = 1; off < 64; off <<= 1) {
        float o = __shfl_down(t, off, 64);
        if (lane + off < 64) t += o;
    }
    float acc = t - sum;   // exclusive suffix (sum of lanes > lane)
#pragma unroll
    for (int k = 31; k >= 0; --k) { acc += v[k]; v[k] = acc; }
#pragma unroll
    for (int q = 0; q < 4; ++q) {
        short8 o;
#pragma unroll
        for (int k = 0; k < 8; ++k) o[k] = f2bf(v[q * 8 + k]);
        *(short8*)(vp + q * 8) = o;
    }
}

// ---------------------------------------------------------------------------
// K3: M[i][j] = sum_t Ktd[i][t]*Vtd[j][t] via MFMA; cross-wave LDS reduce
// -> Mpart has 4 slices. (R12-proven)
// ---------------------------------------------------------------------------
__global__ __launch_bounds__(256) void kvm_mfma(const ushort* __restrict__ Kt,
                                                const ushort* __restrict__ Vt,
                                                float* __restrict__ Mpart) {
    __shared__ float red[2][4096];   // 32 KB
    const int bh = blockIdx.x, kb = blockIdx.y;
    const int tid = threadIdx.x, wave = tid >> 6, lane = tid & 63;
    const int slice = kb * 4 + wave;
    const ushort* Kp = Kt + (size_t)bh * HD * S;
    const ushort* Vp = Vt + (size_t)bh * HD * S;
    f32x4 acc[4][4] = {};
    const int il = lane & 15, g = lane >> 4;
    const int tbase = slice * 128 + g * 8;
#pragma unroll
    for (int ks = 0; ks < 4; ++ks) {
        const int t = tbase + ks * 32;
        short8 af[4], bfv[4];
#pragma unroll
        for (int m = 0; m < 4; ++m) af[m]  = *(const short8*)&Kp[(size_t)(m * 16 + il) * S + t];
#pragma unroll
        for (int n = 0; n < 4; ++n) bfv[n] = *(const short8*)&Vp[(size_t)(n * 16 + il) * S + t];
#pragma unroll
        for (int m = 0; m < 4; ++m)
#pragma unroll
            for (int n = 0; n < 4; ++n)
                acc[m][n] = __builtin_amdgcn_mfma_f32_16x16x32_bf16(af[m], bfv[n], acc[m][n], 0, 0, 0);
    }
#define DUMP(dstbuf)                                                        \
    { float* _d = (dstbuf);                                                 \
      _Pragma("unroll") for (int m = 0; m < 4; ++m)                         \
      _Pragma("unroll") for (int n = 0; n < 4; ++n)                         \
      _Pragma("unroll") for (int j = 0; j < 4; ++j)                         \
          _d[(m * 16 + g * 4 + j) * 64 + n * 16 + il] = acc[m][n][j]; }
#define ADDIN(srcbuf)                                                       \
    { const float* _s = (srcbuf);                                           \
      _Pragma("unroll") for (int m = 0; m < 4; ++m)                         \
      _Pragma("unroll") for (int n = 0; n < 4; ++n)                         \
      _Pragma("unroll") for (int j = 0; j < 4; ++j)                         \
          acc[m][n][j] += _s[(m * 16 + g * 4 + j) * 64 + n * 16 + il]; }
    if (wave == 1) DUMP(red[0]);
    if (wave == 3) DUMP(red[1]);
    __syncthreads();
    if (wave == 0) ADDIN(red[0]);
    if (wave == 2) ADDIN(red[1]);
    __syncthreads();
    if (wave == 2) DUMP(red[0]);
    __syncthreads();
    if (wave == 0) {
        ADDIN(red[0]);
        float* Mp = Mpart + ((size_t)kb * 32 + bh) * 4096;
#pragma unroll
        for (int m = 0; m < 4; ++m)
#pragma unroll
            for (int n = 0; n < 4; ++n)
#pragma unroll
                for (int j = 0; j < 4; ++j)
                    Mp[(m * 16 + g * 4 + j) * 64 + n * 16 + il] = acc[m][n][j];
    }
#undef DUMP
#undef ADDIN
}

// ---------------------------------------------------------------------------
// K4: out = scale * Q·M via MFMA; folds the 4-slice Mpart reduce. (R12)
// ---------------------------------------------------------------------------
__global__ __launch_bounds__(256) void qm_mfma(const ushort* __restrict__ Qb,
                                               const float* __restrict__ Mpart,
                                               float* __restrict__ out) {
    __shared__ ushort Mt[64][72];   // Mt[d][i] = M[i][d], bf16
    const int bh = blockIdx.x, b = bh >> 4, h = bh & 15;
    const int tid = threadIdx.x;
    {
        const int i = tid >> 2, jq = (tid & 3) * 16;
        f32x4 s0 = {}, s1 = {}, s2 = {}, s3 = {};
#pragma unroll
        for (int sl = 0; sl < 4; ++sl) {
            const float* p = Mpart + ((size_t)sl * 32 + bh) * 4096 + i * 64 + jq;
            s0 += *(const f32x4*)(p);
            s1 += *(const f32x4*)(p + 4);
            s2 += *(const f32x4*)(p + 8);
            s3 += *(const f32x4*)(p + 12);
        }
#pragma unroll
        for (int k = 0; k < 4; ++k) {
            Mt[jq + 0  + k][i] = f2bf(s0[k]);
            Mt[jq + 4  + k][i] = f2bf(s1[k]);
            Mt[jq + 8  + k][i] = f2bf(s2[k]);
            Mt[jq + 12 + k][i] = f2bf(s3[k]);
        }
    }
    __syncthreads();
    const int wave = tid >> 6, lane = tid & 63;
    const int sl15 = lane & 15, koct = (lane >> 4) * 8;
    const int s0b = blockIdx.y * 256 + wave * 64;
    f32x4 acc[4][4] = {};
#pragma unroll
    for (int ks = 0; ks < 2; ++ks) {
        short8 af[4], bfv[4];
#pragma unroll
        for (int m = 0; m < 4; ++m) {
            int s = s0b + m * 16 + sl15;
            af[m] = *(const short8*)&Qb[((size_t)bh * S + s) * HD + ks * 32 + koct];
        }
#pragma unroll
        for (int n = 0; n < 4; ++n)
            bfv[n] = *(const short8*)&Mt[n * 16 + sl15][ks * 32 + koct];
#pragma unroll
        for (int m = 0; m < 4; ++m)
#pragma unroll
            for (int n = 0; n < 4; ++n)
                acc[m][n] = __builtin_amdgcn_mfma_f32_16x16x32_bf16(af[m], bfv[n], acc[m][n], 0, 0, 0);
    }
    const float scale = 0.125f * 0.02209708691207961f;  // HD^-0.5 * S^-0.5
#pragma unroll
    for (int m = 0; m < 4; ++m)
#pragma unroll
        for (int n = 0; n < 4; ++n)
#pragma unroll
            for (int j = 0; j < 4; ++j) {
                int s = s0b + m * 16 + (lane >> 4) * 4 + j;
                int d = n * 16 + sl15;
                out[(size_t)(s * B + b) * H + h * 64 + d] = acc[m][n][j] * scale;
            }
}

// ---------------------------------------------------------------------------
extern "C" void kernel_launch(void* const* d_in, const int* in_sizes, int n_in,
                              void* d_out, int out_size, void* d_ws, size_t ws_size,
                              hipStream_t stream) {
    const float* hidden = (const float*)d_in[0];
    const float* W      = (const float*)d_in[1];
    const float* bias   = (const float*)d_in[2];
    float* out = (float*)d_out;

    ushort* Qb    = (ushort*)d_ws;                      //  8 MB  [bh][s][d]
    ushort* Ktd   = Qb + 4194304;                       //  8 MB  [bh][d][t]
    ushort* Vtd   = Ktd + 4194304;                      //  8 MB  [bh][d][t] (scan in place)
    float*  Mpart = (float*)(Vtd + 4194304);            //  2 MB  [4][bh][64][64]
    ushort* Abf   = (ushort*)(Mpart + 524288);          //  8 MB
    ushort* Wbf   = Abf + 4194304;                      //  6 MB
    // total ~40 MB of d_ws

    cast_both<<<(N8_A + N8_W + 255) / 256, 256, 0, stream>>>(hidden, W, Abf, Wbf);
    qkv_gemm_mfma<<<dim3(ROWS / 128, THREE_H / 128), 512, 0, stream>>>(Abf, Wbf, bias, Qb, Ktd, Vtd);
    vscan<<<512, 256, 0, stream>>>(Vtd);
    kvm_mfma<<<dim3(32, 4), 256, 0, stream>>>(Ktd, Vtd, Mpart);
    qm_mfma<<<dim3(32, 8), 256, 0, stream>>>(Qb, Mpart, out);
}

// Round 15
// 73.582 us; speedup vs baseline: 1.0394x; 1.0226x over previous
//
#include <hip/hip_runtime.h>

#define S 2048
#define B 2
#define H 1024
#define NH 16
#define HD 64
#define THREE_H 3072
#define ROWS (S*B)   // 4096

typedef __attribute__((ext_vector_type(8))) short short8;
typedef __attribute__((ext_vector_type(4))) float f32x4;
typedef const __attribute__((address_space(1))) unsigned int* gptr_t;
typedef __attribute__((address_space(3))) unsigned int* lptr_t;

#define N8_A (ROWS * H / 8)        // 524288
#define N8_W (THREE_H * H / 8)     // 393216

__device__ __forceinline__ ushort f2bf(float f) {
    union { float f; unsigned u; } v; v.f = f;
    unsigned r = v.u + 0x7fffu + ((v.u >> 16) & 1u);
    return (ushort)(r >> 16);
}
__device__ __forceinline__ float bf2f(ushort u) {
    union { unsigned u; float f; } v; v.u = ((unsigned)u) << 16;
    return v.f;
}

// ---------------------------------------------------------------------------
// Cast f32 -> bf16 for A and W in one launch (R12-proven)
// ---------------------------------------------------------------------------
__global__ void cast_both(const float* __restrict__ A, const float* __restrict__ W,
                          ushort* __restrict__ Ab, ushort* __restrict__ Wb) {
    int i = blockIdx.x * 256 + threadIdx.x;
    const float4* s4;
    ushort* dst;
    if (i < N8_A) { s4 = (const float4*)A; dst = Ab; }
    else if (i < N8_A + N8_W) { s4 = (const float4*)W; dst = Wb; i -= N8_A; }
    else return;
    float4 a = s4[2 * i], b = s4[2 * i + 1];
    short8 o;
    o[0] = f2bf(a.x); o[1] = f2bf(a.y); o[2] = f2bf(a.z); o[3] = f2bf(a.w);
    o[4] = f2bf(b.x); o[5] = f2bf(b.y); o[6] = f2bf(b.z); o[7] = f2bf(b.w);
    *(short8*)(dst + 8 * (size_t)i) = o;
}

// ---------------------------------------------------------------------------
// K1: bf16 MFMA GEMM, 8-phase counted-vmcnt schedule (T3+T4+T5).
// BM=256 BN=192 BK=64 -> grid 16x16 = 256 blocks = exactly 1/CU.
// 8 waves (2 wr x 4 wc), per-wave 128x48 (8x3 frags). LDS 112 KB dbuf.
// Per period (2 K-tiles): 8 phases, each {stage ~2 gload_lds, ds_read
// subtile, 12 MFMA setprio-wrapped, s_barrier}; vmcnt(2) at ph0/ph4 only.
// Stage windows verified: every stage targets a region last read >= 1
// closing-barrier earlier. {vmcnt;barrier} pairs gate new-buffer reads.
// Swizzle: BK=64 rows, content(row,slot)=slot^(row&7) (R7: 0 conflicts).
// ---------------------------------------------------------------------------
__global__ __launch_bounds__(512, 1) void qkv_gemm_mfma(const ushort* __restrict__ Abf,
                                                        const ushort* __restrict__ Wbf,
                                                        const float* __restrict__ bias,
                                                        ushort* __restrict__ Qb,
                                                        ushort* __restrict__ Ktd,
                                                        ushort* __restrict__ Vtd) {
    __shared__ ushort Abuf[2][256 * 64];   // 64 KB
    __shared__ ushort Bbuf[2][192 * 64];   // 48 KB
    const int tid = threadIdx.x;
    const int wave = tid >> 6, lane = tid & 63;
    const int wr = wave >> 2, wc = wave & 3;        // 2x4 wave grid
    const int row0 = blockIdx.x * 256;
    const int col0 = blockIdx.y * 192;

    f32x4 acc[8][3] = {};

    const int srow = lane >> 3;                     // 0..7 row within 8-row slice
    const int gk = ((lane & 7) ^ srow) * 8;         // inverse-swizzled source octet
    const int il = lane & 15, ko = lane >> 4;

    // staging addresses: chunk c = 64 rows; each wave stages 8 rows/chunk
    size_t aSrc[4], bSrc[3];
    int dOff[4];
#pragma unroll
    for (int c = 0; c < 4; ++c) {
        aSrc[c] = (size_t)(row0 + c * 64 + wave * 8 + srow) * H + gk;
        dOff[c] = (c * 64 + wave * 8) * 64 + lane * 8;
    }
#pragma unroll
    for (int c = 0; c < 3; ++c)
        bSrc[c] = (size_t)(col0 + c * 64 + wave * 8 + srow) * H + gk;

#define GLD(srcp, dstp) __builtin_amdgcn_global_load_lds((gptr_t)(srcp), (lptr_t)(dstp), 16, 0, 0)
#define ST_A(BUF, T, C) GLD(&Abf[aSrc[C] + (size_t)(T) * 64], &Abuf[BUF][dOff[C]])
#define ST_B(BUF, T, C) GLD(&Wbf[bSrc[C] + (size_t)(T) * 64], &Bbuf[BUF][dOff[C]])

#define PHASE(BUF, MH, KH, READB, BREG, STAGE_STMT)                          \
    {                                                                        \
        STAGE_STMT;                                                          \
        short8 af[4];                                                        \
        _Pragma("unroll") for (int mf = 0; mf < 4; ++mf) {                   \
            int ar = wr * 128 + (MH) * 64 + mf * 16 + il;                    \
            af[mf] = *(const short8*)&Abuf[BUF][ar * 64 + (((KH) * 4 + ko) ^ (ar & 7)) * 8]; \
        }                                                                    \
        if (READB) {                                                         \
            _Pragma("unroll") for (int nf = 0; nf < 3; ++nf) {               \
                int br = wc * 48 + nf * 16 + il;                             \
                BREG[nf] = *(const short8*)&Bbuf[BUF][br * 64 + (((KH) * 4 + ko) ^ (br & 7)) * 8]; \
            }                                                                \
        }                                                                    \
        __builtin_amdgcn_s_setprio(1);                                       \
        _Pragma("unroll") for (int mf = 0; mf < 4; ++mf)                     \
            _Pragma("unroll") for (int nf = 0; nf < 3; ++nf)                 \
                acc[(MH) * 4 + mf][nf] = __builtin_amdgcn_mfma_f32_16x16x32_bf16( \
                    af[mf], BREG[nf], acc[(MH) * 4 + mf][nf], 0, 0, 0);      \
        __builtin_amdgcn_s_setprio(0);                                       \
        asm volatile("s_barrier" ::: "memory");                              \
    }

    // prologue (FIFO order matters): Ah0(0), Ah1(0), B(0), Ah0(1) = 9 loads
    ST_A(0, 0, 0); ST_A(0, 0, 2);
    ST_A(0, 0, 1); ST_A(0, 0, 3);
    ST_B(0, 0, 0); ST_B(0, 0, 1); ST_B(0, 0, 2);
    ST_A(1, 1, 0); ST_A(1, 1, 2);

    short8 bfr0[3], bfr1[3];
    for (int p = 0; p < 8; ++p) {
        const int T = 2 * p;
        // ---- ph0: need tile T fully landed (allow Ah0(T+1) in flight) ----
        asm volatile("s_waitcnt vmcnt(2)" ::: "memory");
        asm volatile("s_barrier" ::: "memory");
        PHASE(0, 0, 0, true,  bfr0, { ST_A(1, T + 1, 1); ST_A(1, T + 1, 3); });
        // ---- ph1 ----
        PHASE(0, 1, 0, false, bfr0, { ST_B(1, T + 1, 0); ST_B(1, T + 1, 1); ST_B(1, T + 1, 2); });
        // ---- ph2 ----
        PHASE(0, 0, 1, true,  bfr1, {});
        // ---- ph3: buf0.A.h0 free after ph2 ----
        PHASE(0, 1, 1, false, bfr1, { if (p < 7) { ST_A(0, T + 2, 0); ST_A(0, T + 2, 2); } });
        // ---- ph4: need tile T+1 landed (allow Ah0(T+2) in flight) ----
        if (p < 7) { asm volatile("s_waitcnt vmcnt(2)" ::: "memory"); }
        else       { asm volatile("s_waitcnt vmcnt(0)" ::: "memory"); }
        asm volatile("s_barrier" ::: "memory");
        PHASE(1, 0, 0, true,  bfr0, { if (p < 7) { ST_A(0, T + 2, 1); ST_A(0, T + 2, 3); } });
        // ---- ph5 ----
        PHASE(1, 1, 0, false, bfr0, { if (p < 7) { ST_B(0, T + 2, 0); ST_B(0, T + 2, 1); ST_B(0, T + 2, 2); } });
        // ---- ph6 ----
        PHASE(1, 0, 1, true,  bfr1, {});
        // ---- ph7: buf1.A.h0 free after ph6 ----
        PHASE(1, 1, 1, false, bfr1, { if (p < 7) { ST_A(1, T + 3, 0); ST_A(1, T + 3, 2); } });
    }
#undef PHASE
#undef ST_A
#undef ST_B
#undef GLD

    // ---- epilogue (R12-proven scatter; rows = wr*128 + mi*16) ----
#pragma unroll
    for (int nf = 0; nf < 3; ++nf) {
        int cbase = col0 + wc * 48 + nf * 16;    // 16-col group within one 64-seg
        int h   = cbase / 192;
        int r3  = cbase % 192;
        int sel = r3 >> 6;                       // 0=q 1=k 2=v, wave-uniform
        int d   = (r3 & 63) + il;
        float bv = bias[cbase + il];
        if (sel == 0) {
#pragma unroll
            for (int mi = 0; mi < 8; ++mi) {
                int rowb = row0 + wr * 128 + mi * 16 + ko * 4;
#pragma unroll
                for (int j = 0; j < 4; ++j) {
                    int r = rowb + j;
                    int s = r >> 1, b = r & 1;   // r = s*B + b, B=2
                    Qb[((size_t)((b * NH + h) * S + s)) * HD + d] = f2bf(acc[mi][nf][j] + bv);
                }
            }
        } else {
            ushort* dst = (sel == 1) ? Ktd : Vtd;
            const size_t ro0 = ((size_t)(h)      * HD + d) * S;   // b=0 row
            const size_t ro1 = ((size_t)(NH + h) * HD + d) * S;   // b=1 row
#pragma unroll
            for (int mi = 0; mi < 8; ++mi) {
                int t0 = (row0 + wr * 128 + mi * 16 + ko * 4) >> 1;  // even
                uint lo = (uint)f2bf(acc[mi][nf][0] + bv) |
                          ((uint)f2bf(acc[mi][nf][2] + bv) << 16);   // t0,t0+1 (b=0)
                uint hi = (uint)f2bf(acc[mi][nf][1] + bv) |
                          ((uint)f2bf(acc[mi][nf][3] + bv) << 16);   // t0,t0+1 (b=1)
                *(uint*)&dst[ro0 + t0] = lo;
                *(uint*)&dst[ro1 + t0] = hi;
            }
        }
    }
}

// ---------------------------------------------------------------------------
// V suffix-scan, one wave per (bh,d) row of 2048 t, in place on Vtd. (R12)
// ---------------------------------------------------------------------------
__global__ __launch_bounds__(256) void vscan(ushort* __restrict__ Vtd) {
    const int row = blockIdx.x * 4 + (threadIdx.x >> 6);  // 0..2047 = bh*64+d
    const int lane = threadIdx.x & 63;
    ushort* vp = Vtd + (size_t)row * S + lane * 32;
    float v[32];
#pragma unroll
    for (int q = 0; q < 4; ++q) {
        short8 x = *(const short8*)(vp + q * 8);
#pragma unroll
        for (int k = 0; k < 8; ++k) v[q * 8 + k] = bf2f((ushort)x[k]);
    }
    float sum = 0.f;
#pragma unroll
    for (int k = 0; k < 32; ++k) sum += v[k];
    float t = sum;
#pragma unroll
    for (int off = 1; off < 64; off <<= 1) {
        float o = __shfl_down(t, off, 64);
        if (lane + off < 64) t += o;
    }
    float acc = t - sum;   // exclusive suffix (sum of lanes > lane)
#pragma unroll
    for (int k = 31; k >= 0; --k) { acc += v[k]; v[k] = acc; }
#pragma unroll
    for (int q = 0; q < 4; ++q) {
        short8 o;
#pragma unroll
        for (int k = 0; k < 8; ++k) o[k] = f2bf(v[q * 8 + k]);
        *(short8*)(vp + q * 8) = o;
    }
}

// ---------------------------------------------------------------------------
// K3: M[i][j] = sum_t Ktd[i][t]*Vtd[j][t] via MFMA; cross-wave LDS reduce
// -> Mpart has 4 slices. (R12-proven)
// ---------------------------------------------------------------------------
__global__ __launch_bounds__(256) void kvm_mfma(const ushort* __restrict__ Kt,
                                                const ushort* __restrict__ Vt,
                                                float* __restrict__ Mpart) {
    __shared__ float red[2][4096];   // 32 KB
    const int bh = blockIdx.x, kb = blockIdx.y;
    const int tid = threadIdx.x, wave = tid >> 6, lane = tid & 63;
    const int slice = kb * 4 + wave;
    const ushort* Kp = Kt + (size_t)bh * HD * S;
    const ushort* Vp = Vt + (size_t)bh * HD * S;
    f32x4 acc[4][4] = {};
    const int il = lane & 15, g = lane >> 4;
    const int tbase = slice * 128 + g * 8;
#pragma unroll
    for (int ks = 0; ks < 4; ++ks) {
        const int t = tbase + ks * 32;
        short8 af[4], bfv[4];
#pragma unroll
        for (int m = 0; m < 4; ++m) af[m]  = *(const short8*)&Kp[(size_t)(m * 16 + il) * S + t];
#pragma unroll
        for (int n = 0; n < 4; ++n) bfv[n] = *(const short8*)&Vp[(size_t)(n * 16 + il) * S + t];
#pragma unroll
        for (int m = 0; m < 4; ++m)
#pragma unroll
            for (int n = 0; n < 4; ++n)
                acc[m][n] = __builtin_amdgcn_mfma_f32_16x16x32_bf16(af[m], bfv[n], acc[m][n], 0, 0, 0);
    }
#define DUMP(dstbuf)                                                        \
    { float* _d = (dstbuf);                                                 \
      _Pragma("unroll") for (int m = 0; m < 4; ++m)                         \
      _Pragma("unroll") for (int n = 0; n < 4; ++n)                         \
      _Pragma("unroll") for (int j = 0; j < 4; ++j)                         \
          _d[(m * 16 + g * 4 + j) * 64 + n * 16 + il] = acc[m][n][j]; }
#define ADDIN(srcbuf)                                                       \
    { const float* _s = (srcbuf);                                           \
      _Pragma("unroll") for (int m = 0; m < 4; ++m)                         \
      _Pragma("unroll") for (int n = 0; n < 4; ++n)                         \
      _Pragma("unroll") for (int j = 0; j < 4; ++j)                         \
          acc[m][n][j] += _s[(m * 16 + g * 4 + j) * 64 + n * 16 + il]; }
    if (wave == 1) DUMP(red[0]);
    if (wave == 3) DUMP(red[1]);
    __syncthreads();
    if (wave == 0) ADDIN(red[0]);
    if (wave == 2) ADDIN(red[1]);
    __syncthreads();
    if (wave == 2) DUMP(red[0]);
    __syncthreads();
    if (wave == 0) {
        ADDIN(red[0]);
        float* Mp = Mpart + ((size_t)kb * 32 + bh) * 4096;
#pragma unroll
        for (int m = 0; m < 4; ++m)
#pragma unroll
            for (int n = 0; n < 4; ++n)
#pragma unroll
                for (int j = 0; j < 4; ++j)
                    Mp[(m * 16 + g * 4 + j) * 64 + n * 16 + il] = acc[m][n][j];
    }
#undef DUMP
#undef ADDIN
}

// ---------------------------------------------------------------------------
// K4: out = scale * Q·M via MFMA; folds the 4-slice Mpart reduce. (R12)
// ---------------------------------------------------------------------------
__global__ __launch_bounds__(256) void qm_mfma(const ushort* __restrict__ Qb,
                                               const float* __restrict__ Mpart,
                                               float* __restrict__ out) {
    __shared__ ushort Mt[64][72];   // Mt[d][i] = M[i][d], bf16
    const int bh = blockIdx.x, b = bh >> 4, h = bh & 15;
    const int tid = threadIdx.x;
    {
        const int i = tid >> 2, jq = (tid & 3) * 16;
        f32x4 s0 = {}, s1 = {}, s2 = {}, s3 = {};
#pragma unroll
        for (int sl = 0; sl < 4; ++sl) {
            const float* p = Mpart + ((size_t)sl * 32 + bh) * 4096 + i * 64 + jq;
            s0 += *(const f32x4*)(p);
            s1 += *(const f32x4*)(p + 4);
            s2 += *(const f32x4*)(p + 8);
            s3 += *(const f32x4*)(p + 12);
        }
#pragma unroll
        for (int k = 0; k < 4; ++k) {
            Mt[jq + 0  + k][i] = f2bf(s0[k]);
            Mt[jq + 4  + k][i] = f2bf(s1[k]);
            Mt[jq + 8  + k][i] = f2bf(s2[k]);
            Mt[jq + 12 + k][i] = f2bf(s3[k]);
        }
    }
    __syncthreads();
    const int wave = tid >> 6, lane = tid & 63;
    const int sl15 = lane & 15, koct = (lane >> 4) * 8;
    const int s0b = blockIdx.y * 256 + wave * 64;
    f32x4 acc[4][4] = {};
#pragma unroll
    for (int ks = 0; ks < 2; ++ks) {
        short8 af[4], bfv[4];
#pragma unroll
        for (int m = 0; m < 4; ++m) {
            int s = s0b + m * 16 + sl15;
            af[m] = *(const short8*)&Qb[((size_t)bh * S + s) * HD + ks * 32 + koct];
        }
#pragma unroll
        for (int n = 0; n < 4; ++n)
            bfv[n] = *(const short8*)&Mt[n * 16 + sl15][ks * 32 + koct];
#pragma unroll
        for (int m = 0; m < 4; ++m)
#pragma unroll
            for (int n = 0; n < 4; ++n)
                acc[m][n] = __builtin_amdgcn_mfma_f32_16x16x32_bf16(af[m], bfv[n], acc[m][n], 0, 0, 0);
    }
    const float scale = 0.125f * 0.02209708691207961f;  // HD^-0.5 * S^-0.5
#pragma unroll
    for (int m = 0; m < 4; ++m)
#pragma unroll
        for (int n = 0; n < 4; ++n)
#pragma unroll
            for (int j = 0; j < 4; ++j) {
                int s = s0b + m * 16 + (lane >> 4) * 4 + j;
                int d = n * 16 + sl15;
                out[(size_t)(s * B + b) * H + h * 64 + d] = acc[m][n][j] * scale;
            }
}

// ---------------------------------------------------------------------------
extern "C" void kernel_launch(void* const* d_in, const int* in_sizes, int n_in,
                              void* d_out, int out_size, void* d_ws, size_t ws_size,
                              hipStream_t stream) {
    const float* hidden = (const float*)d_in[0];
    const float* W      = (const float*)d_in[1];
    const float* bias   = (const float*)d_in[2];
    float* out = (float*)d_out;

    ushort* Qb    = (ushort*)d_ws;                      //  8 MB  [bh][s][d]
    ushort* Ktd   = Qb + 4194304;                       //  8 MB  [bh][d][t]
    ushort* Vtd   = Ktd + 4194304;                      //  8 MB  [bh][d][t] (scan in place)
    float*  Mpart = (float*)(Vtd + 4194304);            //  2 MB  [4][bh][64][64]
    ushort* Abf   = (ushort*)(Mpart + 524288);          //  8 MB
    ushort* Wbf   = Abf + 4194304;                      //  6 MB
    // total ~40 MB of d_ws

    cast_both<<<(N8_A + N8_W + 255) / 256, 256, 0, stream>>>(hidden, W, Abf, Wbf);
    qkv_gemm_mfma<<<dim3(ROWS / 256, THREE_H / 192), 512, 0, stream>>>(Abf, Wbf, bias, Qb, Ktd, Vtd);
    vscan<<<512, 256, 0, stream>>>(Vtd);
    kvm_mfma<<<dim3(32, 4), 256, 0, stream>>>(Ktd, Vtd, Mpart);
    qm_mfma<<<dim3(32, 8), 256, 0, stream>>>(Qb, Mpart, out);
}